// Round 1
// baseline (951.068 us; speedup 1.0000x reference)
//
#include <hip/hip_runtime.h>

#define VV 25
#define CC 64
#define DD 128
#define NN 16384
#define NVS 409600
#define VC 1600
#define VD 3200
#define EPSF 1e-5f

// ws layout (float offsets)
#define WS_MASK   0
#define WS_WPACK  1600
#define WS_DWPACK 5696
#define WS_ABY    9792
#define WS_ABR    16192
#define WS_YP     16448
#define WS_RP     (16448 + 512*6400)

typedef __attribute__((ext_vector_type(8))) short s16x8;
typedef __attribute__((ext_vector_type(4))) short s16x4;
typedef __attribute__((ext_vector_type(4))) float f32x4;

__device__ __forceinline__ short f2bf(float f) {
  unsigned u = __builtin_bit_cast(unsigned, f);
  u += 0x7fffu + ((u >> 16) & 1u);
  return (short)(u >> 16);
}
__device__ __forceinline__ float bf2f(short s) {
  unsigned u = ((unsigned)(unsigned short)s) << 16;
  return __builtin_bit_cast(float, u);
}

// ---------------- init: mask = tanh(fm)+1, pack W and down_w into MFMA B-fragment order ----------------
// B-frag layout assumed: lane holds B[k=(lane>>4)*8+j][n=lane&15], frag index = nt*2+kstep
__global__ void k_init(const float* __restrict__ fm, const float* __restrict__ W,
                       const float* __restrict__ dw, float* __restrict__ ws) {
  int g = blockIdx.x * 256 + threadIdx.x;
  if (g < VC) ws[WS_MASK + g] = tanhf(fm[g]) + 1.0f;
  if (g >= 2048 && g < 3072) {
    int idx = g - 2048;
    int frag = idx >> 6, lane = idx & 63;
    int nt = frag >> 1, k = frag & 1, q = lane >> 4, l = lane & 15;
    s16x8 pk;
#pragma unroll
    for (int j = 0; j < 8; j++) {
      int c = k * 32 + q * 8 + j;
      pk[j] = f2bf(W[c * DD + nt * 16 + l]);   // B1[k=c][n=d] = W[c][d]
    }
    ((s16x8*)(ws + WS_WPACK))[idx] = pk;
  }
  if (g >= 3072 && g < 4096) {
    int idx = g - 3072;
    int frag = idx >> 6, lane = idx & 63;
    int nt = frag >> 1, k = frag & 1, q = lane >> 4, l = lane & 15;
    s16x8 pk;
#pragma unroll
    for (int j = 0; j < 8; j++) {
      int c = k * 32 + q * 8 + j;
      pk[j] = f2bf(dw[(nt * 16 + l) * CC + c]); // B2[k=c][n=d] = down_w[d][c]
    }
    ((s16x8*)(ws + WS_DWPACK))[idx] = pk;
  }
}

// ---------------- pass 1: batch stats of raw y (pre-bias) and raw res ----------------
// persistent grid 512 blocks, 4 chunks x 8 rows each. v-major half tiles (8 real rows + 8 zero).
__launch_bounds__(256, 2)
__global__ void k_stats(const float* __restrict__ x0, float* __restrict__ ws) {
  __shared__ short s_raw[200 * 72];
  __shared__ short s_xm[200 * 72];
  __shared__ short s_zero[96];
  int tid = threadIdx.x;
  int wave = tid >> 6, lane = tid & 63, quad = lane >> 4, l15 = lane & 15;
  for (int t = tid; t < 96; t += 256) s_zero[t] = 0;
  const s16x8* wpack = (const s16x8*)(ws + WS_WPACK);
  const s16x8* dwpack = (const s16x8*)(ws + WS_DWPACK);
  const float* mask = ws + WS_MASK;

  float yS[2][25], yQ[2][25];
  float rS[2] = {0.f, 0.f}, rQ[2] = {0.f, 0.f};
#pragma unroll
  for (int a = 0; a < 2; a++)
#pragma unroll
    for (int v = 0; v < 25; v++) { yS[a][v] = 0.f; yQ[a][v] = 0.f; }

  int nt0 = wave * 2;
  s16x8 bw[2][2], bd[2][2];
#pragma unroll
  for (int a = 0; a < 2; a++) {
    int nt = nt0 + a;
    bw[a][0] = wpack[(nt * 2 + 0) * 64 + lane];
    bw[a][1] = wpack[(nt * 2 + 1) * 64 + lane];
    bd[a][0] = dwpack[(nt * 2 + 0) * 64 + lane];
    bd[a][1] = dwpack[(nt * 2 + 1) * 64 + lane];
  }

  for (int chunk = 0; chunk < 4; chunk++) {
    int n0 = blockIdx.x * 32 + chunk * 8;
    __syncthreads();
    // stage raw rows (bf16), layout slot = v*8 + nl, padded row stride 72
    for (int t = tid; t < 3200; t += 256) {
      int flat = t * 4;
      const float4 xv = *(const float4*)(x0 + (size_t)n0 * VC + flat);
      int nl = flat / VC;
      int j = flat - nl * VC;
      int v = j >> 6, c = j & 63;
      s16x4 pk; pk[0]=f2bf(xv.x); pk[1]=f2bf(xv.y); pk[2]=f2bf(xv.z); pk[3]=f2bf(xv.w);
      *(s16x4*)(s_raw + (v * 8 + nl) * 72 + c) = pk;
    }
    __syncthreads();
    // build gathered+masked xm
    for (int t = tid; t < 3200; t += 256) {
      int flat = t * 4;
      int nl = flat / VC;
      int f = flat - nl * VC;
      int v = f >> 6, c = f & 63;
      const float4 mk = *(const float4*)(mask + f);
      float mka[4] = {mk.x, mk.y, mk.z, mk.w};
      s16x4 pk;
#pragma unroll
      for (int jj = 0; jj < 4; jj++) {
        int cc = c + jj;
        int p = (f + jj + (cc << 6)) % VC;   // (v*64 + cc*65) mod 1600
        float xv = bf2f(s_raw[((p >> 6) * 8 + nl) * 72 + (p & 63)]);
        pk[jj] = f2bf(xv * mka[jj]);
      }
      *(s16x4*)(s_xm + (v * 8 + nl) * 72 + c) = pk;
    }
    __syncthreads();
#pragma unroll
    for (int a = 0; a < 2; a++) {
#pragma unroll
      for (int v = 0; v < 25; v++) {
        const short* bx = (l15 < 8) ? (const short*)(s_xm + (v * 8 + l15) * 72) : (const short*)s_zero;
        const short* br = (l15 < 8) ? (const short*)(s_raw + (v * 8 + l15) * 72) : (const short*)s_zero;
        s16x8 a0 = *(const s16x8*)(bx + quad * 8);
        s16x8 a1 = *(const s16x8*)(bx + 32 + quad * 8);
        f32x4 acc = {0.f, 0.f, 0.f, 0.f};
        acc = __builtin_amdgcn_mfma_f32_16x16x32_bf16(a0, bw[a][0], acc, 0, 0, 0);
        acc = __builtin_amdgcn_mfma_f32_16x16x32_bf16(a1, bw[a][1], acc, 0, 0, 0);
        float s1 = acc[0] + acc[1] + acc[2] + acc[3];
        float s2 = acc[0]*acc[0] + acc[1]*acc[1] + acc[2]*acc[2] + acc[3]*acc[3];
        s1 += __shfl_xor(s1, 16, 64); s1 += __shfl_xor(s1, 32, 64);
        s2 += __shfl_xor(s2, 16, 64); s2 += __shfl_xor(s2, 32, 64);
        yS[a][v] += s1; yQ[a][v] += s2;
        s16x8 r0 = *(const s16x8*)(br + quad * 8);
        s16x8 r1 = *(const s16x8*)(br + 32 + quad * 8);
        f32x4 rc = {0.f, 0.f, 0.f, 0.f};
        rc = __builtin_amdgcn_mfma_f32_16x16x32_bf16(r0, bd[a][0], rc, 0, 0, 0);
        rc = __builtin_amdgcn_mfma_f32_16x16x32_bf16(r1, bd[a][1], rc, 0, 0, 0);
        float t1 = rc[0]+rc[1]+rc[2]+rc[3];
        float t2 = rc[0]*rc[0]+rc[1]*rc[1]+rc[2]*rc[2]+rc[3]*rc[3];
        t1 += __shfl_xor(t1, 16, 64); t1 += __shfl_xor(t1, 32, 64);
        t2 += __shfl_xor(t2, 16, 64); t2 += __shfl_xor(t2, 32, 64);
        rS[a] += t1; rQ[a] += t2;
      }
    }
  }
  if (quad == 0) {
    float* yp = ws + WS_YP + (size_t)blockIdx.x * 6400;
    float* rp = ws + WS_RP + (size_t)blockIdx.x * 256;
#pragma unroll
    for (int a = 0; a < 2; a++) {
      int nt = nt0 + a;
#pragma unroll
      for (int v = 0; v < 25; v++) {
        int f = v * 128 + nt * 16 + l15;
        *(float2*)(yp + f * 2) = make_float2(yS[a][v], yQ[a][v]);
      }
      int dd = nt * 16 + l15;
      *(float2*)(rp + dd * 2) = make_float2(rS[a], rQ[a]);
    }
  }
}

// ---------------- reduce partials -> per-feature affine (a,b); biases cancel under BN ----------------
__global__ void k_reduce(const float* __restrict__ gamma, const float* __restrict__ beta,
                         const float* __restrict__ dgamma, const float* __restrict__ dbeta,
                         float* __restrict__ ws) {
  if (blockIdx.x == 13) {
    int dd = threadIdx.x;
    if (dd < 128) {
      const float2* rp = (const float2*)(ws + WS_RP);
      float s1 = 0.f, s2 = 0.f;
#pragma unroll 8
      for (int b = 0; b < 512; b++) { float2 v = rp[b * 128 + dd]; s1 += v.x; s2 += v.y; }
      float mean = s1 * (1.0f / 409600.0f);
      float var = s2 * (1.0f / 409600.0f) - mean * mean;
      float rs = rsqrtf(var + EPSF);
      float a = dgamma[dd] * rs;
      ((float2*)(ws + WS_ABR))[dd] = make_float2(a, dbeta[dd] - mean * a);
    }
    return;
  }
  int f = blockIdx.x * 256 + threadIdx.x;
  if (f >= VD) return;
  const float2* yp = (const float2*)(ws + WS_YP);
  float s1 = 0.f, s2 = 0.f;
#pragma unroll 8
  for (int b = 0; b < 512; b++) { float2 v = yp[(size_t)b * 3200 + f]; s1 += v.x; s2 += v.y; }
  float mean = s1 * (1.0f / 16384.0f);
  float var = s2 * (1.0f / 16384.0f) - mean * mean;
  float rs = rsqrtf(var + EPSF);
  int d = f & 127, vv = f >> 7;
  int vo = vv + d % 25; if (vo >= 25) vo -= 25;
  int j = vo * 128 + d;                  // gamma/beta index after shift_out
  float a = gamma[j] * rs;
  ((float2*)(ws + WS_ABY))[f] = make_float2(a, beta[j] - mean * a);
}

// ---------------- pass 2: recompute, normalize, shift-scatter, add, relu, write ----------------
__launch_bounds__(256, 2)
__global__ void k_main(const float* __restrict__ x0, const float* __restrict__ ws,
                       float* __restrict__ out) {
  __shared__ short s_raw[112 * 72];
  __shared__ short s_xm[112 * 72];
  __shared__ short s_ybuf[100 * 129];
  int tid = threadIdx.x;
  int wave = tid >> 6, lane = tid & 63, quad = lane >> 4, l15 = lane & 15;
  int n0 = blockIdx.x * 4;
  const float* mask = ws + WS_MASK;
  // stage (n-major: slot = nl*25 + v)
  for (int t = tid; t < 1600; t += 256) {
    int flat = t * 4;
    const float4 xv = *(const float4*)(x0 + (size_t)n0 * VC + flat);
    int nl = flat / VC;
    int j = flat - nl * VC;
    int v = j >> 6, c = j & 63;
    s16x4 pk; pk[0]=f2bf(xv.x); pk[1]=f2bf(xv.y); pk[2]=f2bf(xv.z); pk[3]=f2bf(xv.w);
    *(s16x4*)(s_raw + (nl * 25 + v) * 72 + c) = pk;
  }
  __syncthreads();
  for (int t = tid; t < 1600; t += 256) {
    int flat = t * 4;
    int nl = flat / VC;
    int f = flat - nl * VC;
    int v = f >> 6, c = f & 63;
    const float4 mk = *(const float4*)(mask + f);
    float mka[4] = {mk.x, mk.y, mk.z, mk.w};
    s16x4 pk;
#pragma unroll
    for (int jj = 0; jj < 4; jj++) {
      int cc = c + jj;
      int p = (f + jj + (cc << 6)) % VC;
      float xv = bf2f(s_raw[(nl * 25 + (p >> 6)) * 72 + (p & 63)]);
      pk[jj] = f2bf(xv * mka[jj]);
    }
    *(s16x4*)(s_xm + (nl * 25 + v) * 72 + c) = pk;
  }
  __syncthreads();
  const s16x8* wpack = (const s16x8*)(ws + WS_WPACK);
  const float2* aby = (const float2*)(ws + WS_ABY);
  // phase 2: y path -> normalized, scattered into ybuf at (v'+d)%25
  {
    s16x8 b0, b1;
#pragma unroll
    for (int ji = 0; ji < 14; ji++) {
      int job = wave * 14 + ji;
      int nt = job / 7, mt = job - nt * 7;
      if (ji == 0 || ji == 7) {
        b0 = wpack[(nt * 2 + 0) * 64 + lane];
        b1 = wpack[(nt * 2 + 1) * 64 + lane];
      }
      int mbase = mt * 16;
      const short* pa = s_xm + (mbase + l15) * 72 + quad * 8;
      s16x8 a0 = *(const s16x8*)(pa);
      s16x8 a1 = *(const s16x8*)(pa + 32);
      f32x4 acc = {0.f, 0.f, 0.f, 0.f};
      acc = __builtin_amdgcn_mfma_f32_16x16x32_bf16(a0, b0, acc, 0, 0, 0);
      acc = __builtin_amdgcn_mfma_f32_16x16x32_bf16(a1, b1, acc, 0, 0, 0);
      int d = nt * 16 + l15;
      int d25 = d % 25;
#pragma unroll
      for (int i = 0; i < 4; i++) {
        int s = mbase + quad * 4 + i;
        if (s < 100) {
          int r = s / 25;
          int vv = s - r * 25;
          float2 ab = aby[vv * 128 + d];
          float val = acc[i] * ab.x + ab.y;
          int vo = vv + d25; if (vo >= 25) vo -= 25;
          s_ybuf[(r * 25 + vo) * 129 + d] = f2bf(val);
        }
      }
    }
  }
  __syncthreads();
  const s16x8* dwpack = (const s16x8*)(ws + WS_DWPACK);
  const float2* abr = (const float2*)(ws + WS_ABR);
  // phase 3: res path -> normalize, add into ybuf in place, relu
  {
    s16x8 b0, b1; float2 ab = make_float2(0.f, 0.f);
#pragma unroll
    for (int ji = 0; ji < 14; ji++) {
      int job = wave * 14 + ji;
      int nt = job / 7, mt = job - nt * 7;
      if (ji == 0 || ji == 7) {
        b0 = dwpack[(nt * 2 + 0) * 64 + lane];
        b1 = dwpack[(nt * 2 + 1) * 64 + lane];
        ab = abr[nt * 16 + l15];
      }
      int mbase = mt * 16;
      const short* pa = s_raw + (mbase + l15) * 72 + quad * 8;
      s16x8 a0 = *(const s16x8*)(pa);
      s16x8 a1 = *(const s16x8*)(pa + 32);
      f32x4 acc = {0.f, 0.f, 0.f, 0.f};
      acc = __builtin_amdgcn_mfma_f32_16x16x32_bf16(a0, b0, acc, 0, 0, 0);
      acc = __builtin_amdgcn_mfma_f32_16x16x32_bf16(a1, b1, acc, 0, 0, 0);
      int d = nt * 16 + l15;
#pragma unroll
      for (int i = 0; i < 4; i++) {
        int s = mbase + quad * 4 + i;
        if (s < 100) {
          int r = s / 25;
          int vv = s - r * 25;
          int ad = (r * 25 + vv) * 129 + d;
          float val = acc[i] * ab.x + ab.y + bf2f(s_ybuf[ad]);
          val = fmaxf(val, 0.0f);
          s_ybuf[ad] = f2bf(val);
        }
      }
    }
  }
  __syncthreads();
  // phase 4: coalesced writeout. out[b][d][t0+tr][v], q = tr*25+v contiguous
  int b = n0 >> 9, t0 = n0 & 511;
  float* ob = out + (size_t)b * 1638400 + (size_t)t0 * 25;
  for (int idx = tid; idx < 12800; idx += 256) {
    int dd = idx / 100;
    int q = idx - dd * 100;
    ob[(size_t)dd * 12800 + q] = bf2f(s_ybuf[q * 129 + dd]);
  }
}

extern "C" void kernel_launch(void* const* d_in, const int* in_sizes, int n_in,
                              void* d_out, int out_size, void* d_ws, size_t ws_size,
                              hipStream_t stream) {
  const float* x0    = (const float*)d_in[0];
  const float* fm    = (const float*)d_in[1];
  const float* W     = (const float*)d_in[2];
  const float* bn_g  = (const float*)d_in[4];
  const float* bn_b  = (const float*)d_in[5];
  const float* dw    = (const float*)d_in[6];
  const float* dbn_g = (const float*)d_in[8];
  const float* dbn_b = (const float*)d_in[9];
  float* ws = (float*)d_ws;
  float* out = (float*)d_out;
  k_init<<<16, 256, 0, stream>>>(fm, W, dw, ws);
  k_stats<<<512, 256, 0, stream>>>(x0, ws);
  k_reduce<<<14, 256, 0, stream>>>(bn_g, bn_b, dbn_g, dbn_b, ws);
  k_main<<<4096, 256, 0, stream>>>(x0, ws, out);
}

// Round 2
// 643.361 us; speedup vs baseline: 1.4783x; 1.4783x over previous
//
#include <hip/hip_runtime.h>

#define VV 25
#define CC 64
#define DD 128
#define NN 16384
#define NVS 409600
#define VC 1600
#define VD 3200
#define EPSF 1e-5f

// ws layout (float offsets)
#define WS_MASK   0
#define WS_WPACK  1600
#define WS_DWPACK 5696
#define WS_ABY    9792
#define WS_ABR    16192
#define WS_COLSUM 16448
#define WS_QY     18048
#define WS_QR     21248
// zero region: [WS_COLSUM, WS_COLSUM+4928)

typedef __attribute__((ext_vector_type(8))) short s16x8;
typedef __attribute__((ext_vector_type(4))) short s16x4;
typedef __attribute__((ext_vector_type(4))) float f32x4;

__device__ __forceinline__ short f2bf(float f) {
  unsigned u = __builtin_bit_cast(unsigned, f);
  u += 0x7fffu + ((u >> 16) & 1u);
  return (short)(u >> 16);
}
__device__ __forceinline__ float bf2f(short s) {
  unsigned u = ((unsigned)(unsigned short)s) << 16;
  return __builtin_bit_cast(float, u);
}

// ---------------- init: mask, pack W/down_w into B-fragments, zero stat accumulators ----------------
__global__ void k_init(const float* __restrict__ fm, const float* __restrict__ W,
                       const float* __restrict__ dw, float* __restrict__ ws) {
  int g = blockIdx.x * 256 + threadIdx.x;
  if (g < VC) ws[WS_MASK + g] = tanhf(fm[g]) + 1.0f;
  if (g < 4928) ws[WS_COLSUM + g] = 0.0f;
  if (g >= 2048 && g < 3072) {
    int idx = g - 2048;
    int frag = idx >> 6, lane = idx & 63;
    int nt = frag >> 1, k = frag & 1, q = lane >> 4, l = lane & 15;
    s16x8 pk;
#pragma unroll
    for (int j = 0; j < 8; j++) {
      int c = k * 32 + q * 8 + j;
      pk[j] = f2bf(W[c * DD + nt * 16 + l]);   // B1[k=c][n=d] = W[c][d]
    }
    ((s16x8*)(ws + WS_WPACK))[idx] = pk;
  }
  if (g >= 3072 && g < 4096) {
    int idx = g - 3072;
    int frag = idx >> 6, lane = idx & 63;
    int nt = frag >> 1, k = frag & 1, q = lane >> 4, l = lane & 15;
    s16x8 pk;
#pragma unroll
    for (int j = 0; j < 8; j++) {
      int c = k * 32 + q * 8 + j;
      pk[j] = f2bf(dw[(nt * 16 + l) * CC + c]); // B2[k=c][n=d] = down_w[d][c]
    }
    ((s16x8*)(ws + WS_DWPACK))[idx] = pk;
  }
}

// ---------------- pass 1: colsum(x0) + sum y^2 per (v,d) + sum res^2 per d ----------------
// LDS accumulators (no per-thread stat arrays -> no spill); flush via global float atomics.
__launch_bounds__(256, 2)
__global__ void k_stats(const float* __restrict__ x0, float* __restrict__ ws) {
  __shared__ short s_raw[200 * 72];
  __shared__ short s_xm[200 * 72];
  __shared__ short s_zero[96];
  __shared__ float s_col[1600];
  __shared__ float s_qy[3200];
  int tid = threadIdx.x;
  int wave = tid >> 6, lane = tid & 63, quad = lane >> 4, l15 = lane & 15;
  for (int t = tid; t < 96; t += 256) s_zero[t] = 0;
  for (int t = tid; t < 1600; t += 256) s_col[t] = 0.0f;
  for (int t = tid; t < 3200; t += 256) s_qy[t] = 0.0f;
  const s16x8* wpack = (const s16x8*)(ws + WS_WPACK);
  const s16x8* dwpack = (const s16x8*)(ws + WS_DWPACK);
  const float* mask = ws + WS_MASK;

  int nt0 = wave * 2;
  s16x8 bw[2][2], bd[2][2];
#pragma unroll
  for (int a = 0; a < 2; a++) {
    int nt = nt0 + a;
    bw[a][0] = wpack[(nt * 2 + 0) * 64 + lane];
    bw[a][1] = wpack[(nt * 2 + 1) * 64 + lane];
    bd[a][0] = dwpack[(nt * 2 + 0) * 64 + lane];
    bd[a][1] = dwpack[(nt * 2 + 1) * 64 + lane];
  }
  float rq[2] = {0.f, 0.f};

  for (int chunk = 0; chunk < 4; chunk++) {
    int n0 = blockIdx.x * 32 + chunk * 8;
    __syncthreads();
    // stage raw rows (bf16, v-major slot = v*8+nl, stride 72) + fp32 colsum accumulation
    for (int t = tid; t < 3200; t += 256) {
      int flat = t * 4;
      const float4 xv = *(const float4*)(x0 + (size_t)n0 * VC + flat);
      int nl = flat / VC;
      int j = flat - nl * VC;
      int v = j >> 6, c = j & 63;
      s16x4 pk; pk[0]=f2bf(xv.x); pk[1]=f2bf(xv.y); pk[2]=f2bf(xv.z); pk[3]=f2bf(xv.w);
      *(s16x4*)(s_raw + (v * 8 + nl) * 72 + c) = pk;
      atomicAdd(&s_col[j + 0], xv.x);
      atomicAdd(&s_col[j + 1], xv.y);
      atomicAdd(&s_col[j + 2], xv.z);
      atomicAdd(&s_col[j + 3], xv.w);
    }
    __syncthreads();
    // build gathered+masked xm
    for (int t = tid; t < 3200; t += 256) {
      int flat = t * 4;
      int nl = flat / VC;
      int f = flat - nl * VC;
      int v = f >> 6, c = f & 63;
      const float4 mk = *(const float4*)(mask + f);
      float mka[4] = {mk.x, mk.y, mk.z, mk.w};
      s16x4 pk;
#pragma unroll
      for (int jj = 0; jj < 4; jj++) {
        int cc = c + jj;
        int p = (f + jj + (cc << 6)) % VC;   // (v*64 + cc*65) mod 1600
        float xv = bf2f(s_raw[((p >> 6) * 8 + nl) * 72 + (p & 63)]);
        pk[jj] = f2bf(xv * mka[jj]);
      }
      *(s16x4*)(s_xm + (v * 8 + nl) * 72 + c) = pk;
    }
    __syncthreads();
#pragma unroll 1
    for (int v = 0; v < 25; v++) {
      const short* bx = (l15 < 8) ? (const short*)(s_xm + (v * 8 + l15) * 72) : (const short*)s_zero;
      const short* br = (l15 < 8) ? (const short*)(s_raw + (v * 8 + l15) * 72) : (const short*)s_zero;
      s16x8 a0 = *(const s16x8*)(bx + quad * 8);
      s16x8 a1 = *(const s16x8*)(bx + 32 + quad * 8);
      s16x8 r0 = *(const s16x8*)(br + quad * 8);
      s16x8 r1 = *(const s16x8*)(br + 32 + quad * 8);
#pragma unroll
      for (int a = 0; a < 2; a++) {
        f32x4 acc = {0.f, 0.f, 0.f, 0.f};
        acc = __builtin_amdgcn_mfma_f32_16x16x32_bf16(a0, bw[a][0], acc, 0, 0, 0);
        acc = __builtin_amdgcn_mfma_f32_16x16x32_bf16(a1, bw[a][1], acc, 0, 0, 0);
        float q = acc[0]*acc[0] + acc[1]*acc[1] + acc[2]*acc[2] + acc[3]*acc[3];
        q += __shfl_xor(q, 16, 64); q += __shfl_xor(q, 32, 64);
        if (quad == 0) atomicAdd(&s_qy[v * 128 + (nt0 + a) * 16 + l15], q);
        f32x4 rc = {0.f, 0.f, 0.f, 0.f};
        rc = __builtin_amdgcn_mfma_f32_16x16x32_bf16(r0, bd[a][0], rc, 0, 0, 0);
        rc = __builtin_amdgcn_mfma_f32_16x16x32_bf16(r1, bd[a][1], rc, 0, 0, 0);
        rq[a] += rc[0]*rc[0] + rc[1]*rc[1] + rc[2]*rc[2] + rc[3]*rc[3];
      }
    }
  }
  __syncthreads();
  // flush block partials to global accumulators
  for (int t = tid; t < 1600; t += 256) atomicAdd(ws + WS_COLSUM + t, s_col[t]);
  for (int t = tid; t < 3200; t += 256) atomicAdd(ws + WS_QY + t, s_qy[t]);
#pragma unroll
  for (int a = 0; a < 2; a++) {
    float q = rq[a];
    q += __shfl_xor(q, 16, 64); q += __shfl_xor(q, 32, 64);
    if (quad == 0) atomicAdd(ws + WS_QR + (nt0 + a) * 16 + l15, q);
  }
}

// ---------------- reduce: reconstruct means from colsum (linearity), fold into affine (a,b) ----------------
// grid 26 x 128. blocks 0..24: y features (3200); block 25: res features (128)
__global__ void k_reduce(const float* __restrict__ gamma, const float* __restrict__ beta,
                         const float* __restrict__ dgamma, const float* __restrict__ dbeta,
                         const float* __restrict__ W, const float* __restrict__ dw,
                         float* __restrict__ ws) {
  if (blockIdx.x == 25) {
    __shared__ float s_cs[64];
    int t = threadIdx.x;
    if (t < 64) {
      float s = 0.f;
#pragma unroll
      for (int v = 0; v < 25; v++) s += ws[WS_COLSUM + v * 64 + t];
      s_cs[t] = s;
    }
    __syncthreads();
    int d = t;
    float m = 0.f;
#pragma unroll 8
    for (int c = 0; c < 64; c++) m += s_cs[c] * dw[d * 64 + c];
    m *= (1.0f / 409600.0f);
    float q = ws[WS_QR + d] * (1.0f / 409600.0f);
    float var = q - m * m;
    float rs = rsqrtf(var + EPSF);
    float a = dgamma[d] * rs;
    ((float2*)(ws + WS_ABR))[d] = make_float2(a, dbeta[d] - m * a);
    return;
  }
  int f = blockIdx.x * 128 + threadIdx.x;   // 0..3199
  int v = f >> 7, d = f & 127;
  float m = 0.f;
#pragma unroll 8
  for (int c = 0; c < 64; c++) {
    int p = (v * 64 + 65 * c) % VC;
    m += ws[WS_COLSUM + p] * ws[WS_MASK + v * 64 + c] * W[c * DD + d];
  }
  m *= (1.0f / 16384.0f);
  float q = ws[WS_QY + f] * (1.0f / 16384.0f);
  float var = q - m * m;
  float rs = rsqrtf(var + EPSF);
  int vo = v + d % 25; if (vo >= 25) vo -= 25;
  int j = vo * 128 + d;                  // gamma/beta index after shift_out
  float a = gamma[j] * rs;
  ((float2*)(ws + WS_ABY))[f] = make_float2(a, beta[j] - m * a);
}

// ---------------- pass 2: recompute, normalize, shift-scatter, add, relu, write ----------------
__launch_bounds__(256, 2)
__global__ void k_main(const float* __restrict__ x0, const float* __restrict__ ws,
                       float* __restrict__ out) {
  __shared__ short s_raw[112 * 72];
  __shared__ short s_xm[112 * 72];
  __shared__ short s_ybuf[100 * 129];
  int tid = threadIdx.x;
  int wave = tid >> 6, lane = tid & 63, quad = lane >> 4, l15 = lane & 15;
  int n0 = blockIdx.x * 4;
  const float* mask = ws + WS_MASK;
  // stage (n-major: slot = nl*25 + v)
  for (int t = tid; t < 1600; t += 256) {
    int flat = t * 4;
    const float4 xv = *(const float4*)(x0 + (size_t)n0 * VC + flat);
    int nl = flat / VC;
    int j = flat - nl * VC;
    int v = j >> 6, c = j & 63;
    s16x4 pk; pk[0]=f2bf(xv.x); pk[1]=f2bf(xv.y); pk[2]=f2bf(xv.z); pk[3]=f2bf(xv.w);
    *(s16x4*)(s_raw + (nl * 25 + v) * 72 + c) = pk;
  }
  __syncthreads();
  for (int t = tid; t < 1600; t += 256) {
    int flat = t * 4;
    int nl = flat / VC;
    int f = flat - nl * VC;
    int v = f >> 6, c = f & 63;
    const float4 mk = *(const float4*)(mask + f);
    float mka[4] = {mk.x, mk.y, mk.z, mk.w};
    s16x4 pk;
#pragma unroll
    for (int jj = 0; jj < 4; jj++) {
      int cc = c + jj;
      int p = (f + jj + (cc << 6)) % VC;
      float xv = bf2f(s_raw[(nl * 25 + (p >> 6)) * 72 + (p & 63)]);
      pk[jj] = f2bf(xv * mka[jj]);
    }
    *(s16x4*)(s_xm + (nl * 25 + v) * 72 + c) = pk;
  }
  __syncthreads();
  const s16x8* wpack = (const s16x8*)(ws + WS_WPACK);
  const float2* aby = (const float2*)(ws + WS_ABY);
  // phase 2: y path -> normalized, scattered into ybuf at (v'+d)%25
  {
    s16x8 b0, b1;
#pragma unroll
    for (int ji = 0; ji < 14; ji++) {
      int job = wave * 14 + ji;
      int nt = job / 7, mt = job - nt * 7;
      if (ji == 0 || ji == 7) {
        b0 = wpack[(nt * 2 + 0) * 64 + lane];
        b1 = wpack[(nt * 2 + 1) * 64 + lane];
      }
      int mbase = mt * 16;
      const short* pa = s_xm + (mbase + l15) * 72 + quad * 8;
      s16x8 a0 = *(const s16x8*)(pa);
      s16x8 a1 = *(const s16x8*)(pa + 32);
      f32x4 acc = {0.f, 0.f, 0.f, 0.f};
      acc = __builtin_amdgcn_mfma_f32_16x16x32_bf16(a0, b0, acc, 0, 0, 0);
      acc = __builtin_amdgcn_mfma_f32_16x16x32_bf16(a1, b1, acc, 0, 0, 0);
      int d = nt * 16 + l15;
      int d25 = d % 25;
#pragma unroll
      for (int i = 0; i < 4; i++) {
        int s = mbase + quad * 4 + i;
        if (s < 100) {
          int r = s / 25;
          int vv = s - r * 25;
          float2 ab = aby[vv * 128 + d];
          float val = acc[i] * ab.x + ab.y;
          int vo = vv + d25; if (vo >= 25) vo -= 25;
          s_ybuf[(r * 25 + vo) * 129 + d] = f2bf(val);
        }
      }
    }
  }
  __syncthreads();
  const s16x8* dwpack = (const s16x8*)(ws + WS_DWPACK);
  const float2* abr = (const float2*)(ws + WS_ABR);
  // phase 3: res path -> normalize, add into ybuf in place, relu
  {
    s16x8 b0, b1; float2 ab = make_float2(0.f, 0.f);
#pragma unroll
    for (int ji = 0; ji < 14; ji++) {
      int job = wave * 14 + ji;
      int nt = job / 7, mt = job - nt * 7;
      if (ji == 0 || ji == 7) {
        b0 = dwpack[(nt * 2 + 0) * 64 + lane];
        b1 = dwpack[(nt * 2 + 1) * 64 + lane];
        ab = abr[nt * 16 + l15];
      }
      int mbase = mt * 16;
      const short* pa = s_raw + (mbase + l15) * 72 + quad * 8;
      s16x8 a0 = *(const s16x8*)(pa);
      s16x8 a1 = *(const s16x8*)(pa + 32);
      f32x4 acc = {0.f, 0.f, 0.f, 0.f};
      acc = __builtin_amdgcn_mfma_f32_16x16x32_bf16(a0, b0, acc, 0, 0, 0);
      acc = __builtin_amdgcn_mfma_f32_16x16x32_bf16(a1, b1, acc, 0, 0, 0);
      int d = nt * 16 + l15;
#pragma unroll
      for (int i = 0; i < 4; i++) {
        int s = mbase + quad * 4 + i;
        if (s < 100) {
          int r = s / 25;
          int vv = s - r * 25;
          int ad = (r * 25 + vv) * 129 + d;
          float val = acc[i] * ab.x + ab.y + bf2f(s_ybuf[ad]);
          val = fmaxf(val, 0.0f);
          s_ybuf[ad] = f2bf(val);
        }
      }
    }
  }
  __syncthreads();
  // phase 4: coalesced writeout. out[b][d][t0+tr][v], q = tr*25+v contiguous
  int b = n0 >> 9, t0 = n0 & 511;
  float* ob = out + (size_t)b * 1638400 + (size_t)t0 * 25;
  for (int idx = tid; idx < 12800; idx += 256) {
    int dd = idx / 100;
    int q = idx - dd * 100;
    ob[(size_t)dd * 12800 + q] = bf2f(s_ybuf[q * 129 + dd]);
  }
}

extern "C" void kernel_launch(void* const* d_in, const int* in_sizes, int n_in,
                              void* d_out, int out_size, void* d_ws, size_t ws_size,
                              hipStream_t stream) {
  const float* x0    = (const float*)d_in[0];
  const float* fm    = (const float*)d_in[1];
  const float* W     = (const float*)d_in[2];
  const float* bn_g  = (const float*)d_in[4];
  const float* bn_b  = (const float*)d_in[5];
  const float* dw    = (const float*)d_in[6];
  const float* dbn_g = (const float*)d_in[8];
  const float* dbn_b = (const float*)d_in[9];
  float* ws = (float*)d_ws;
  float* out = (float*)d_out;
  k_init<<<20, 256, 0, stream>>>(fm, W, dw, ws);
  k_stats<<<512, 256, 0, stream>>>(x0, ws);
  k_reduce<<<26, 128, 0, stream>>>(bn_g, bn_b, dbn_g, dbn_b, W, dw, ws);
  k_main<<<4096, 256, 0, stream>>>(x0, ws, out);
}

// Round 3
// 617.768 us; speedup vs baseline: 1.5395x; 1.0414x over previous
//
#include <hip/hip_runtime.h>

#define VC 1600
#define EPSF 1e-5f

// ws layout (float offsets)
#define WS_MASKJ  0
#define WS_WPACK  1600
#define WS_DWPACK 5696
#define WS_ABY    9792
#define WS_ABR    16192
#define WS_COLSUM 16448
#define WS_QYP    18048
#define QYP_STRIDE 3328

typedef __attribute__((ext_vector_type(8))) short s16x8;
typedef __attribute__((ext_vector_type(4))) short s16x4;
typedef __attribute__((ext_vector_type(4))) float f32x4;

__device__ __forceinline__ short f2bf(float f) {
  unsigned u = __builtin_bit_cast(unsigned, f);
  u += 0x7fffu + ((u >> 16) & 1u);
  return (short)(u >> 16);
}
__device__ __forceinline__ float bf2f(short s) {
  unsigned u = ((unsigned)(unsigned short)s) << 16;
  return __builtin_bit_cast(float, u);
}

// stage one float4: raw (contiguous) + masked scatter to gathered position.
// raw slot = base + u*vstr ; gathered slot = base + v(j)*vstr
__device__ __forceinline__ void stage_elem(int j, int base, int vstr, float4 xv,
                                           const float* mj, short* s_raw, short* s_xm) {
  int u = j >> 6, c = j & 63;
  s16x4 pk; pk[0]=f2bf(xv.x); pk[1]=f2bf(xv.y); pk[2]=f2bf(xv.z); pk[3]=f2bf(xv.w);
  *(s16x4*)(s_raw + (base + u*vstr)*72 + c) = pk;
  int v0 = (u - c + 75) % 25;
  float xa[4] = {xv.x, xv.y, xv.z, xv.w};
#pragma unroll
  for (int e = 0; e < 4; e++) {
    int ve = v0 - e; if (ve < 0) ve += 25;
    s_xm[(base + ve*vstr)*72 + c + e] = f2bf(xa[e] * mj[e]);
  }
}

// ---------------- init: maskJ (dest-indexed mask in source order), packs, zero colsum ----------------
__global__ void k_init(const float* __restrict__ fm, const float* __restrict__ W,
                       const float* __restrict__ dw, float* __restrict__ ws) {
  int g = blockIdx.x * 256 + threadIdx.x;
  if (g < VC) {
    int c = g & 63, jv = g >> 6;
    int v = (jv - c + 75) % 25;
    ws[WS_MASKJ + g] = tanhf(fm[v * 64 + c]) + 1.0f;
    ws[WS_COLSUM + g] = 0.0f;
  }
  if (g >= 2048 && g < 3072) {
    int idx = g - 2048;
    int frag = idx >> 6, lane = idx & 63;
    int nt = frag >> 1, k = frag & 1, q = lane >> 4, l = lane & 15;
    s16x8 pk;
#pragma unroll
    for (int j = 0; j < 8; j++) {
      int c = k * 32 + q * 8 + j;
      pk[j] = f2bf(W[c * 128 + nt * 16 + l]);   // B1[k=c][n=d] = W[c][d]
    }
    ((s16x8*)(ws + WS_WPACK))[idx] = pk;
  }
  if (g >= 3072 && g < 4096) {
    int idx = g - 3072;
    int frag = idx >> 6, lane = idx & 63;
    int nt = frag >> 1, k = frag & 1, q = lane >> 4, l = lane & 15;
    s16x8 pk;
#pragma unroll
    for (int j = 0; j < 8; j++) {
      int c = k * 32 + q * 8 + j;
      pk[j] = f2bf(dw[(nt * 16 + l) * 64 + c]); // B2[k=c][n=d] = down_w[d][c]
    }
    ((s16x8*)(ws + WS_DWPACK))[idx] = pk;
  }
}

// ---------------- pass 1: colsum (regs) + sum y^2 per (v,d) + sum res^2 per d ----------------
// v-paired full 16-row tiles; scatter-at-stage gather; plain per-block partial writes.
__launch_bounds__(256, 2)
__global__ void k_stats(const float* __restrict__ x0, float* __restrict__ ws) {
  __shared__ short s_raw[14976];   // 26 v-slots x 8 rows x 72
  __shared__ short s_xm[14976];
  __shared__ float s_qy[3328];     // [0,3200)=y (v,d), [3200,3328)=res d
  int tid = threadIdx.x;
  int wave = tid >> 6, lane = tid & 63, quad = lane >> 4, l15 = lane & 15;
  for (int t = tid; t < 3328; t += 256) s_qy[t] = 0.f;
  for (int t = tid; t < 576; t += 256) { s_raw[14400 + t] = 0; s_xm[14400 + t] = 0; }
  const s16x8* wpack = (const s16x8*)(ws + WS_WPACK);
  const s16x8* dwpack = (const s16x8*)(ws + WS_DWPACK);

  int nt0 = wave * 2;
  s16x8 bw[2][2], bd[2][2];
#pragma unroll
  for (int a = 0; a < 2; a++) {
    int nt = nt0 + a;
    bw[a][0] = wpack[(nt * 2 + 0) * 64 + lane];
    bw[a][1] = wpack[(nt * 2 + 1) * 64 + lane];
    bd[a][0] = dwpack[(nt * 2 + 0) * 64 + lane];
    bd[a][1] = dwpack[(nt * 2 + 1) * 64 + lane];
  }
  float mj0[4], mj1[4];
  {
    float4 m4 = *(const float4*)(ws + WS_MASKJ + tid * 4);
    mj0[0]=m4.x; mj0[1]=m4.y; mj0[2]=m4.z; mj0[3]=m4.w;
  }
  if (tid < 144) {
    float4 m4 = *(const float4*)(ws + WS_MASKJ + 1024 + tid * 4);
    mj1[0]=m4.x; mj1[1]=m4.y; mj1[2]=m4.z; mj1[3]=m4.w;
  }
  float cs[8] = {0,0,0,0,0,0,0,0};
  float rq0 = 0.f, rq1 = 0.f;

  for (int chunk = 0; chunk < 4; chunk++) {
    int n0 = blockIdx.x * 32 + chunk * 8;
    __syncthreads();
    for (int r = 0; r < 8; r++) {
      const float* rowp = x0 + (size_t)(n0 + r) * VC;
      float4 xv = *(const float4*)(rowp + tid * 4);
      cs[0]+=xv.x; cs[1]+=xv.y; cs[2]+=xv.z; cs[3]+=xv.w;
      stage_elem(tid * 4, r, 8, xv, mj0, s_raw, s_xm);
      if (tid < 144) {
        float4 xw = *(const float4*)(rowp + 1024 + tid * 4);
        cs[4]+=xw.x; cs[5]+=xw.y; cs[6]+=xw.z; cs[7]+=xw.w;
        stage_elem(1024 + tid * 4, r, 8, xw, mj1, s_raw, s_xm);
      }
    }
    __syncthreads();
#pragma unroll 1
    for (int vp = 0; vp < 13; vp++) {
      int rb = vp * 16;
      const short* px = s_xm + (rb + l15) * 72 + quad * 8;
      const short* pr = s_raw + (rb + l15) * 72 + quad * 8;
      s16x8 a0 = *(const s16x8*)px;
      s16x8 a1 = *(const s16x8*)(px + 32);
      s16x8 r0 = *(const s16x8*)pr;
      s16x8 r1 = *(const s16x8*)(pr + 32);
      int vq = vp * 2 + (quad >> 1);   // vq==25 tiles are all-zero -> adds 0.0, harmless
#pragma unroll
      for (int a = 0; a < 2; a++) {
        f32x4 acc = {0.f, 0.f, 0.f, 0.f};
        acc = __builtin_amdgcn_mfma_f32_16x16x32_bf16(a0, bw[a][0], acc, 0, 0, 0);
        acc = __builtin_amdgcn_mfma_f32_16x16x32_bf16(a1, bw[a][1], acc, 0, 0, 0);
        float q = acc[0]*acc[0] + acc[1]*acc[1] + acc[2]*acc[2] + acc[3]*acc[3];
        atomicAdd(&s_qy[vq * 128 + (nt0 + a) * 16 + l15], q);
        f32x4 rc = {0.f, 0.f, 0.f, 0.f};
        rc = __builtin_amdgcn_mfma_f32_16x16x32_bf16(r0, bd[a][0], rc, 0, 0, 0);
        rc = __builtin_amdgcn_mfma_f32_16x16x32_bf16(r1, bd[a][1], rc, 0, 0, 0);
        float t2 = rc[0]*rc[0] + rc[1]*rc[1] + rc[2]*rc[2] + rc[3]*rc[3];
        if (a == 0) rq0 += t2; else rq1 += t2;
      }
    }
  }
  __syncthreads();
  atomicAdd(&s_qy[3200 + nt0 * 16 + l15], rq0);
  atomicAdd(&s_qy[3200 + (nt0 + 1) * 16 + l15], rq1);
  __syncthreads();
  float* qp = ws + WS_QYP + (size_t)blockIdx.x * QYP_STRIDE;
  for (int t = tid; t < 3328; t += 256) qp[t] = s_qy[t];
#pragma unroll
  for (int e = 0; e < 4; e++) atomicAdd(ws + WS_COLSUM + tid * 4 + e, cs[e]);
  if (tid < 144) {
#pragma unroll
    for (int e = 0; e < 4; e++) atomicAdd(ws + WS_COLSUM + 1024 + tid * 4 + e, cs[4 + e]);
  }
}

// ---------------- reduce: sum partials, reconstruct means from colsum, fold affine ----------------
__global__ void k_reduce(const float* __restrict__ gamma, const float* __restrict__ beta,
                         const float* __restrict__ dgamma, const float* __restrict__ dbeta,
                         const float* __restrict__ W, const float* __restrict__ dw,
                         float* __restrict__ ws) {
  int tid = threadIdx.x;
  if (blockIdx.x == 25) {
    __shared__ float s_cs[64];
    if (tid < 64) {
      float s = 0.f;
#pragma unroll
      for (int v = 0; v < 25; v++) s += ws[WS_COLSUM + v * 64 + tid];
      s_cs[tid] = s;
    }
    __syncthreads();
    int d = tid;
    float q = 0.f;
#pragma unroll 8
    for (int b2 = 0; b2 < 512; b2++) q += ws[WS_QYP + (size_t)b2 * QYP_STRIDE + 3200 + d];
    float m = 0.f;
#pragma unroll 8
    for (int c = 0; c < 64; c++) m += s_cs[c] * dw[d * 64 + c];
    m *= (1.0f / 409600.0f);
    float var = q * (1.0f / 409600.0f) - m * m;
    float a = dgamma[d] * rsqrtf(var + EPSF);
    ((float2*)(ws + WS_ABR))[d] = make_float2(a, dbeta[d] - m * a);
    return;
  }
  __shared__ float s_cm[1600];
  for (int t = tid; t < 1600; t += 128)
    s_cm[t] = ws[WS_COLSUM + t] * ws[WS_MASKJ + t];
  __syncthreads();
  int f = blockIdx.x * 128 + tid;   // 0..3199
  int v = f >> 7, d = f & 127;
  float q = 0.f;
#pragma unroll 8
  for (int b2 = 0; b2 < 512; b2++) q += ws[WS_QYP + (size_t)b2 * QYP_STRIDE + f];
  float m = 0.f;
  int p = v * 64;
#pragma unroll 8
  for (int c = 0; c < 64; c++) {
    m += s_cm[p] * W[c * 128 + d];
    p += 65; if (p >= VC) p -= VC;
  }
  m *= (1.0f / 16384.0f);
  float var = q * (1.0f / 16384.0f) - m * m;
  int d25 = d % 25;
  int vo = v + d25; if (vo >= 25) vo -= 25;
  int jg = vo * 128 + d;
  float a = gamma[jg] * rsqrtf(var + EPSF);
  ((float2*)(ws + WS_ABY))[f] = make_float2(a, beta[jg] - m * a);
}

// ---------------- pass 2: recompute, normalize, shift-scatter, add, relu, write ----------------
__launch_bounds__(256, 2)
__global__ void k_main(const float* __restrict__ x0, const float* __restrict__ ws,
                       float* __restrict__ out) {
  __shared__ short s_raw[112 * 72];
  __shared__ short s_xm[112 * 72];
  __shared__ short s_ybuf[100 * 129];
  int tid = threadIdx.x;
  int wave = tid >> 6, lane = tid & 63, quad = lane >> 4, l15 = lane & 15;
  int n0 = blockIdx.x * 4;
  // stage: raw contiguous + masked scatter-gather, n-major slot = nl*25 + v
  for (int t = tid; t < 1600; t += 256) {
    int flat = t * 4;
    int nl = flat / VC;
    int j = flat - nl * VC;
    float4 xv = *(const float4*)(x0 + (size_t)n0 * VC + flat);
    float4 m4 = *(const float4*)(ws + WS_MASKJ + j);
    float mj[4] = {m4.x, m4.y, m4.z, m4.w};
    stage_elem(j, nl * 25, 1, xv, mj, s_raw, s_xm);
  }
  __syncthreads();
  const s16x8* wpack = (const s16x8*)(ws + WS_WPACK);
  const float2* aby = (const float2*)(ws + WS_ABY);
  // phase 2: y path -> normalized, scattered into ybuf at (v'+d)%25
  {
    s16x8 b0, b1;
#pragma unroll
    for (int ji = 0; ji < 14; ji++) {
      int job = wave * 14 + ji;
      int nt = job / 7, mt = job - nt * 7;
      if (ji == 0 || ji == 7) {
        b0 = wpack[(nt * 2 + 0) * 64 + lane];
        b1 = wpack[(nt * 2 + 1) * 64 + lane];
      }
      int mbase = mt * 16;
      const short* pa = s_xm + (mbase + l15) * 72 + quad * 8;
      s16x8 a0 = *(const s16x8*)(pa);
      s16x8 a1 = *(const s16x8*)(pa + 32);
      f32x4 acc = {0.f, 0.f, 0.f, 0.f};
      acc = __builtin_amdgcn_mfma_f32_16x16x32_bf16(a0, b0, acc, 0, 0, 0);
      acc = __builtin_amdgcn_mfma_f32_16x16x32_bf16(a1, b1, acc, 0, 0, 0);
      int d = nt * 16 + l15;
      int d25 = d % 25;
#pragma unroll
      for (int i = 0; i < 4; i++) {
        int s = mbase + quad * 4 + i;
        if (s < 100) {
          int r = s / 25;
          int vv = s - r * 25;
          float2 ab = aby[vv * 128 + d];
          float val = acc[i] * ab.x + ab.y;
          int vo = vv + d25; if (vo >= 25) vo -= 25;
          s_ybuf[(r * 25 + vo) * 129 + d] = f2bf(val);
        }
      }
    }
  }
  __syncthreads();
  const s16x8* dwpack = (const s16x8*)(ws + WS_DWPACK);
  const float2* abr = (const float2*)(ws + WS_ABR);
  // phase 3: res path -> normalize, add into ybuf in place, relu
  {
    s16x8 b0, b1; float2 ab = make_float2(0.f, 0.f);
#pragma unroll
    for (int ji = 0; ji < 14; ji++) {
      int job = wave * 14 + ji;
      int nt = job / 7, mt = job - nt * 7;
      if (ji == 0 || ji == 7) {
        b0 = dwpack[(nt * 2 + 0) * 64 + lane];
        b1 = dwpack[(nt * 2 + 1) * 64 + lane];
        ab = abr[nt * 16 + l15];
      }
      int mbase = mt * 16;
      const short* pa = s_raw + (mbase + l15) * 72 + quad * 8;
      s16x8 a0 = *(const s16x8*)(pa);
      s16x8 a1 = *(const s16x8*)(pa + 32);
      f32x4 acc = {0.f, 0.f, 0.f, 0.f};
      acc = __builtin_amdgcn_mfma_f32_16x16x32_bf16(a0, b0, acc, 0, 0, 0);
      acc = __builtin_amdgcn_mfma_f32_16x16x32_bf16(a1, b1, acc, 0, 0, 0);
      int d = nt * 16 + l15;
#pragma unroll
      for (int i = 0; i < 4; i++) {
        int s = mbase + quad * 4 + i;
        if (s < 100) {
          int r = s / 25;
          int vv = s - r * 25;
          int ad = (r * 25 + vv) * 129 + d;
          float val = acc[i] * ab.x + ab.y + bf2f(s_ybuf[ad]);
          val = fmaxf(val, 0.0f);
          s_ybuf[ad] = f2bf(val);
        }
      }
    }
  }
  __syncthreads();
  // phase 4: vectorized coalesced writeout. out[b][d][t0+tr][v], q = tr*25+v
  int b = n0 >> 9, t0 = n0 & 511;
  float* ob = out + (size_t)b * 1638400 + (size_t)t0 * 25;
  for (int it = tid; it < 3200; it += 256) {
    int dd = it / 25;
    int qg = it - dd * 25;
    int q0 = qg * 4;
    float4 o;
    o.x = bf2f(s_ybuf[(q0 + 0) * 129 + dd]);
    o.y = bf2f(s_ybuf[(q0 + 1) * 129 + dd]);
    o.z = bf2f(s_ybuf[(q0 + 2) * 129 + dd]);
    o.w = bf2f(s_ybuf[(q0 + 3) * 129 + dd]);
    *(float4*)(ob + (size_t)dd * 12800 + q0) = o;
  }
}

extern "C" void kernel_launch(void* const* d_in, const int* in_sizes, int n_in,
                              void* d_out, int out_size, void* d_ws, size_t ws_size,
                              hipStream_t stream) {
  const float* x0    = (const float*)d_in[0];
  const float* fm    = (const float*)d_in[1];
  const float* W     = (const float*)d_in[2];
  const float* bn_g  = (const float*)d_in[4];
  const float* bn_b  = (const float*)d_in[5];
  const float* dw    = (const float*)d_in[6];
  const float* dbn_g = (const float*)d_in[8];
  const float* dbn_b = (const float*)d_in[9];
  float* ws = (float*)d_ws;
  float* out = (float*)d_out;
  k_init<<<20, 256, 0, stream>>>(fm, W, dw, ws);
  k_stats<<<512, 256, 0, stream>>>(x0, ws);
  k_reduce<<<26, 128, 0, stream>>>(bn_g, bn_b, dbn_g, dbn_b, W, dw, ws);
  k_main<<<4096, 256, 0, stream>>>(x0, ws, out);
}